// Round 20
// baseline (117.310 us; speedup 1.0000x reference)
//
#include <hip/hip_runtime.h>

#define NN 100000
#define DD 128
#define EE 640000
#define BN_EPS 1e-3f
#define NBLK 391    // ceil(NN/256); #buckets and #sort blocks
#define NTILE 6250  // NN/16 exactly
#define EPB 1637    // edges per sort block: 391*1637 >= EE
#define FFN1_BLKS 768
#define FFN2_BLKS 768

typedef __bf16 bf16x8 __attribute__((ext_vector_type(8)));
typedef __bf16 bf16x2 __attribute__((ext_vector_type(2)));
typedef float f32x4 __attribute__((ext_vector_type(4)));

// ---- workspace byte offsets ----
#define W1F_OFF 0u
#define W2F_OFF 32768u
#define B1F_OFF 98304u
#define B2F_OFF 98816u
#define T_OFF   99328u
#define OFFS_OFF 26099328u    // NN+1 ints
#define ELIST_OFF 26899328u   // EE int; head aliases cntg+bofs (dead before p2)
#define CNTG_OFF ELIST_OFF               // 391*391 int
#define BOFS_OFF (ELIST_OFF + 611524u)   // 391*391 int
#define BSUM_OFF 29459328u
#define AGG_OFF 29464576u     // NN*128 bf16; aliases pairbuf (EE int) before agg runs
#define XB_OFF  55064576u     // NN*128 bf16

// tanh-form gelu; max |err| vs exact ~3e-4 (threshold 9.8e-2)
__device__ __forceinline__ float gelu_fast(float x) {
    float x3 = x * x * x;
    float z2 = 1.5957691216057308f * x + 0.07135481627002407f * x3;
    return x / (1.0f + __expf(-z2));
}

// prep: [0,64) fold_bias | [64,256) fold_w | [256,647) sortA per-slice bucket counts
// T/Agg physical layout (row-major 128 bf16/row): slot p holds logical col
// (2*(p>>5)+(p&1))*16 + ((p>>1)&15)  — matches ffn1's per-wave 4B stores.
__global__ __launch_bounds__(256) void prep_kernel(
    const float* __restrict__ g1, const float* __restrict__ be1,
    const float* __restrict__ m1, const float* __restrict__ v1,
    const float* __restrict__ W1, const float* __restrict__ b1,
    const float* __restrict__ g2, const float* __restrict__ be2,
    const float* __restrict__ m2, const float* __restrict__ v2,
    const float* __restrict__ W2, const float* __restrict__ b2,
    const int* __restrict__ edges,
    __bf16* __restrict__ W1f, __bf16* __restrict__ W2f,
    float* __restrict__ b1f, float* __restrict__ b2f,
    int* __restrict__ cntg)
{
    const int blk = blockIdx.x;
    const int t = threadIdx.x;
    if (blk < 64) {
        const int w = (blk * 256 + t) >> 6;
        const int lane = t & 63;
        if (w < 128) {
            float acc = 0.f;
            for (int k = lane; k < 128; k += 64) {
                float s = g1[k] * rsqrtf(v1[k] + BN_EPS);
                float sh = be1[k] - m1[k] * s;
                acc += sh * W1[k * 128 + w];
            }
#pragma unroll
            for (int off = 32; off > 0; off >>= 1) acc += __shfl_down(acc, off);
            if (lane == 0) b1f[w] = acc + b1[w];
        } else {
            const int n = w - 128;
            float acc = 0.f;
            for (int k = lane; k < 256; k += 64) {
                float s = g2[k] * rsqrtf(v2[k] + BN_EPS);
                float sh = be2[k] - m2[k] * s;
                acc += sh * W2[k * 128 + n];
            }
#pragma unroll
            for (int off = 32; off > 0; off >>= 1) acc += __shfl_down(acc, off);
            if (lane == 0) b2f[n] = acc + b2[n];
        }
    } else if (blk < 256) {
        int tid = (blk - 64) * 256 + t;
        if (tid < 16384) {
            int idx = tid;
            int i = idx & 7, l = (idx >> 3) & 63, nt = (idx >> 9) & 7, kt = idx >> 12;
            int k = kt * 32 + (l >> 4) * 8 + i;
            int n = nt * 16 + (l & 15);
            float s = g1[k] * rsqrtf(v1[k] + BN_EPS);
            W1f[idx] = (__bf16)(s * W1[k * 128 + n]);
        } else {
            int idx = tid - 16384;
            int i = idx & 7, l = (idx >> 3) & 63, nt = (idx >> 9) & 7, kt = idx >> 12;
            int n = nt * 16 + (l & 15);
            int row;
            if (kt < 4) {
                row = kt * 32 + (l >> 4) * 8 + i;
            } else {
                int q = (kt - 4) * 32 + (l >> 4) * 8 + i;      // physical agg slot
                row = 128 + ((2 * (q >> 5) + (q & 1)) * 16 + ((q >> 1) & 15));
            }
            float s = g2[row] * rsqrtf(v2[row] + BN_EPS);
            W2f[idx] = (__bf16)(s * W2[row * 128 + n]);
        }
    } else {
        __shared__ int cnt[NBLK];
        const int k = blk - 256;
        for (int b = t; b < NBLK; b += 256) cnt[b] = 0;
        __syncthreads();
        const int e0 = k * EPB, e1 = min(e0 + EPB, EE);
        for (int e = e0 + t; e < e1; e += 256)
            atomicAdd(&cnt[edges[e] >> 8], 1);
        __syncthreads();
        for (int b = t; b < NBLK; b += 256) cntg[k * NBLK + b] = cnt[b];
    }
}

// sortB: bucket b; exclusive scan of cntg[k][b] over k -> bofs; total -> bsum[b]
__global__ __launch_bounds__(256) void sortb_kernel(const int* __restrict__ cntg,
                                                    int* __restrict__ bofs,
                                                    int* __restrict__ bsum)
{
    const int b = blockIdx.x, t = threadIdx.x;
    __shared__ int sp[256];
    int ia = 2 * t, ib = 2 * t + 1;
    int va = (ia < NBLK) ? cntg[ia * NBLK + b] : 0;
    int vb = (ib < NBLK) ? cntg[ib * NBLK + b] : 0;
    sp[t] = va + vb;
    __syncthreads();
    for (int off = 1; off < 256; off <<= 1) {
        int tmp = (t >= off) ? sp[t - off] : 0;
        __syncthreads();
        sp[t] += tmp;
        __syncthreads();
    }
    int pexcl = sp[t] - (va + vb);
    if (ia < NBLK) bofs[b * NBLK + ia] = pexcl;
    if (ib < NBLK) bofs[b * NBLK + ib] = pexcl + va;
    if (t == 255) bsum[b] = sp[255];
}

// sortC: inline exclusive scan of bsum seeds LDS cursors; scatter edge slice
__global__ __launch_bounds__(256) void sortc_kernel(const int* __restrict__ edges,
                                                    const int* __restrict__ bsum,
                                                    const int* __restrict__ bofs,
                                                    int* __restrict__ pairbuf)
{
    __shared__ int sp[256];
    __shared__ int cur[NBLK];
    const int k = blockIdx.x, t = threadIdx.x;
    int ia = 2 * t, ib = 2 * t + 1;
    int va = (ia < NBLK) ? bsum[ia] : 0;
    int vb = (ib < NBLK) ? bsum[ib] : 0;
    sp[t] = va + vb;
    __syncthreads();
    for (int off = 1; off < 256; off <<= 1) {
        int tmp = (t >= off) ? sp[t - off] : 0;
        __syncthreads();
        sp[t] += tmp;
        __syncthreads();
    }
    int pexcl = sp[t] - (va + vb);
    if (ia < NBLK) cur[ia] = pexcl + bofs[ia * NBLK + k];
    if (ib < NBLK) cur[ib] = pexcl + va + bofs[ib * NBLK + k];
    __syncthreads();
    const int e0 = k * EPB, e1 = min(e0 + EPB, EE);
    for (int e = e0 + t; e < e1; e += 256) {
        int dst = edges[e];
        int src = edges[EE + e];
        int pos = atomicAdd(&cur[dst >> 8], 1);
        pairbuf[pos] = (src << 8) | (dst & 255);
    }
}

// ffn1: persistent-B half-split (wave owns nt=2w,2w+1; 8 B frags in regs),
// grid-stride tiles with named-buffer X prefetch (ffn2's proven loop).
#define FFN1_XLD(TT, RA, RB)                                               \
    {                                                                      \
        const float* xr = X + (size_t)((TT) * 16 + c) * DD + kh * 8;       \
        _Pragma("unroll")                                                  \
        for (int q = 0; q < 4; ++q) {                                      \
            RA[q] = *(const f32x4*)(xr + q * 32);                          \
            RB[q] = *(const f32x4*)(xr + q * 32 + 4);                      \
        }                                                                  \
    }

#define FFN1_CMP(TT, RA, RB)                                               \
    {                                                                      \
        bf16x8 af[4];                                                      \
        _Pragma("unroll")                                                  \
        for (int kt = 0; kt < 4; ++kt) {                                   \
            bf16x8 fa;                                                     \
            _Pragma("unroll")                                              \
            for (int i = 0; i < 4; ++i) {                                  \
                fa[i] = (__bf16)RA[kt][i]; fa[4 + i] = (__bf16)RB[kt][i];  \
            }                                                              \
            af[kt] = fa;                                                   \
        }                                                                  \
        if (w == 0) {                                                      \
            const size_t rowb = (size_t)((TT) * 16 + c) * DD;              \
            _Pragma("unroll")                                              \
            for (int kt = 0; kt < 4; ++kt)                                 \
                *(bf16x8*)(Xb + rowb + kt * 32 + kh * 8) = af[kt];         \
        }                                                                  \
        f32x4 a0 = {}, a1 = {};                                            \
        _Pragma("unroll")                                                  \
        for (int kt = 0; kt < 4; ++kt) {                                   \
            a0 = __builtin_amdgcn_mfma_f32_16x16x32_bf16(af[kt], Bf1[kt][0], a0, 0, 0, 0); \
            a1 = __builtin_amdgcn_mfma_f32_16x16x32_bf16(af[kt], Bf1[kt][1], a1, 0, 0, 0); \
        }                                                                  \
        _Pragma("unroll")                                                  \
        for (int r = 0; r < 4; ++r) {                                      \
            int rowp = (TT) * 16 + kh * 4 + r;                             \
            bf16x2 pk;                                                     \
            pk[0] = (__bf16)gelu_fast(a0[r] + bias0);                      \
            pk[1] = (__bf16)gelu_fast(a1[r] + bias1);                      \
            *(bf16x2*)(T + (size_t)rowp * DD + w * 32 + c * 2) = pk;       \
        }                                                                  \
    }

// fused: [0,NBLK) p2 (bucket-local CSR finalize; 2KB LDS) |
// [NBLK,+768) ffn1 persistent.
__global__ __launch_bounds__(256) void p2_ffn1_kernel(
    const int* __restrict__ bsum, const int* __restrict__ pairbuf,
    int* __restrict__ elist, int* __restrict__ offs,
    const float* __restrict__ X, const __bf16* __restrict__ W1f,
    const float* __restrict__ b1f, __bf16* __restrict__ T,
    __bf16* __restrict__ Xb)
{
    __shared__ int sArr[256];
    __shared__ int cur[256];
    __shared__ int red[4];
    const int t = threadIdx.x;
    if (blockIdx.x < NBLK) {
        const int b = blockIdx.x;
        int part = 0;
        for (int i = t; i < b; i += 256) part += bsum[i];
#pragma unroll
        for (int off = 32; off > 0; off >>= 1) part += __shfl_down(part, off);
        if ((t & 63) == 0) red[t >> 6] = part;
        cur[t] = 0;
        __syncthreads();
        const int start = red[0] + red[1] + red[2] + red[3];
        const int end = start + bsum[b];
        for (int e = start + t; e < end; e += 256)
            atomicAdd(&cur[pairbuf[e] & 255], 1);
        __syncthreads();
        int v = cur[t];
        sArr[t] = v;
        __syncthreads();
        for (int off = 1; off < 256; off <<= 1) {
            int tmp = (t >= off) ? sArr[t - off] : 0;
            __syncthreads();
            sArr[t] += tmp;
            __syncthreads();
        }
        int ex = sArr[t] - v + start;
        const int node = b * 256 + t;
        if (node <= NN) offs[node] = ex;   // node==NN -> sentinel EE
        __syncthreads();
        cur[t] = ex;
        __syncthreads();
        for (int e = start + t; e < end; e += 256) {
            int item = pairbuf[e];
            int pos = atomicAdd(&cur[item & 255], 1);
            elist[pos] = item >> 8;
        }
        return;
    }

    const int w = t >> 6;               // wave = col pair (nt 2w, 2w+1)
    const int lane = t & 63;
    const int c = lane & 15, kh = lane >> 4;

    bf16x8 Bf1[4][2];
#pragma unroll
    for (int kt = 0; kt < 4; ++kt) {
        Bf1[kt][0] = *(const bf16x8*)(W1f + ((size_t)((kt * 8 + w * 2) * 64 + lane)) * 8);
        Bf1[kt][1] = *(const bf16x8*)(W1f + ((size_t)((kt * 8 + w * 2 + 1) * 64 + lane)) * 8);
    }
    const float bias0 = b1f[(w * 2) * 16 + c];
    const float bias1 = b1f[(w * 2 + 1) * 16 + c];

    int tile = blockIdx.x - NBLK;
    f32x4 ra[4], rb[4], sa[4], sb[4];
    FFN1_XLD(tile, ra, rb);
    while (true) {
        int t2 = tile + FFN1_BLKS;
        if (t2 < NTILE) FFN1_XLD(t2, sa, sb);
        FFN1_CMP(tile, ra, rb);
        if (t2 >= NTILE) break;
        int t3 = t2 + FFN1_BLKS;
        if (t3 < NTILE) FFN1_XLD(t3, ra, rb);
        FFN1_CMP(t2, sa, sb);
        if (t3 >= NTILE) break;
        tile = t3;
    }
}

// gather-mean: 16 threads/node; coalesced elist load + __shfl broadcast.
// Layout-agnostic (sums physical slots; W2f fold compensates).
__global__ __launch_bounds__(256) void agg_kernel(
    const __bf16* __restrict__ T, const int* __restrict__ offs,
    const int* __restrict__ elist, __bf16* __restrict__ Agg)
{
    int t = blockIdx.x * 256 + threadIdx.x;
    int node = t >> 4, j = t & 15;
    if (node >= NN) return;
    const int lane = threadIdx.x & 63;
    const int gbase = lane & 48;
    const int beg = offs[node];
    const int end = offs[node + 1];
    const int d = end - beg;
    float acc[8] = {};
    for (int eb = beg; eb < end; eb += 16) {
        int me = eb + (lane & 15);
        int sv = (me < end) ? elist[me] : 0;
        int cnt = min(end - eb, 16);
        int i = 0;
        for (; i + 3 < cnt; i += 4) {
            int s0 = __shfl(sv, gbase + i);
            int s1 = __shfl(sv, gbase + i + 1);
            int s2 = __shfl(sv, gbase + i + 2);
            int s3 = __shfl(sv, gbase + i + 3);
            bf16x8 v0 = *(const bf16x8*)(T + (size_t)s0 * DD + j * 8);
            bf16x8 v1 = *(const bf16x8*)(T + (size_t)s1 * DD + j * 8);
            bf16x8 v2 = *(const bf16x8*)(T + (size_t)s2 * DD + j * 8);
            bf16x8 v3 = *(const bf16x8*)(T + (size_t)s3 * DD + j * 8);
#pragma unroll
            for (int q = 0; q < 8; ++q)
                acc[q] += ((float)v0[q] + (float)v1[q]) + ((float)v2[q] + (float)v3[q]);
        }
        for (; i < cnt; ++i) {
            int s0 = __shfl(sv, gbase + i);
            bf16x8 v0 = *(const bf16x8*)(T + (size_t)s0 * DD + j * 8);
#pragma unroll
            for (int q = 0; q < 8; ++q) acc[q] += (float)v0[q];
        }
    }
    const float inv = 1.0f / fmaxf((float)d, 1.0f);
    bf16x8 o;
#pragma unroll
    for (int q = 0; q < 8; ++q) o[q] = (__bf16)(acc[q] * inv);
    *(bf16x8*)(Agg + (size_t)node * DD + j * 8) = o;
}

// out = gelu([Xb, Agg] @ W2f + b2f); persistent-B quarters, grid-stride tiles,
// next-tile A prefetch (named buffers).
#define FFN2_LOAD(TT, XA, GA)                                              \
    {                                                                      \
        const size_t rb = (size_t)((TT) * 16 + c) * DD + kh * 8;           \
        _Pragma("unroll")                                                  \
        for (int q = 0; q < 4; ++q) {                                      \
            XA[q] = *(const bf16x8*)(Xb + rb + q * 32);                    \
            GA[q] = *(const bf16x8*)(Agg + rb + q * 32);                   \
        }                                                                  \
    }

#define FFN2_COMP(TT, XA, GA)                                              \
    {                                                                      \
        f32x4 acc0 = {}, acc1 = {};                                        \
        _Pragma("unroll")                                                  \
        for (int kt = 0; kt < 4; ++kt) {                                   \
            acc0 = __builtin_amdgcn_mfma_f32_16x16x32_bf16(XA[kt], Bf[kt][0], acc0, 0, 0, 0); \
            acc1 = __builtin_amdgcn_mfma_f32_16x16x32_bf16(XA[kt], Bf[kt][1], acc1, 0, 0, 0); \
        }                                                                  \
        _Pragma("unroll")                                                  \
        for (int kt = 0; kt < 4; ++kt) {                                   \
            acc0 = __builtin_amdgcn_mfma_f32_16x16x32_bf16(GA[kt], Bf[4 + kt][0], acc0, 0, 0, 0); \
            acc1 = __builtin_amdgcn_mfma_f32_16x16x32_bf16(GA[kt], Bf[4 + kt][1], acc1, 0, 0, 0); \
        }                                                                  \
        _Pragma("unroll")                                                  \
        for (int r = 0; r < 4; ++r) {                                      \
            int row = (TT) * 16 + kh * 4 + r;                              \
            out[(size_t)row * DD + (w * 2) * 16 + c] = gelu_fast(acc0[r] + bias0); \
            out[(size_t)row * DD + (w * 2 + 1) * 16 + c] = gelu_fast(acc1[r] + bias1); \
        }                                                                  \
    }

__global__ __launch_bounds__(256) void ffn2_kernel(
    const __bf16* __restrict__ Xb, const __bf16* __restrict__ Agg,
    const __bf16* __restrict__ W2f, const float* __restrict__ b2f,
    float* __restrict__ out)
{
    const int w = threadIdx.x >> 6;        // wave = quarter (nt 2w, 2w+1)
    const int lane = threadIdx.x & 63;
    const int c = lane & 15, kh = lane >> 4;
    const int G = gridDim.x;

    bf16x8 Bf[8][2];
#pragma unroll
    for (int kt = 0; kt < 8; ++kt) {
        Bf[kt][0] = *(const bf16x8*)(W2f + ((size_t)((kt * 8 + w * 2) * 64 + lane)) * 8);
        Bf[kt][1] = *(const bf16x8*)(W2f + ((size_t)((kt * 8 + w * 2 + 1) * 64 + lane)) * 8);
    }
    const float bias0 = b2f[(w * 2) * 16 + c];
    const float bias1 = b2f[(w * 2 + 1) * 16 + c];

    int tile = blockIdx.x;
    if (tile >= NTILE) return;
    bf16x8 xa[4], ga[4], xb2[4], gb[4];
    FFN2_LOAD(tile, xa, ga);
    while (true) {
        int t2 = tile + G;
        if (t2 < NTILE) FFN2_LOAD(t2, xb2, gb);
        FFN2_COMP(tile, xa, ga);
        if (t2 >= NTILE) break;
        int t3 = t2 + G;
        if (t3 < NTILE) FFN2_LOAD(t3, xa, ga);
        FFN2_COMP(t2, xb2, gb);
        if (t3 >= NTILE) break;
        tile = t3;
    }
}

extern "C" void kernel_launch(void* const* d_in, const int* in_sizes, int n_in,
                              void* d_out, int out_size, void* d_ws, size_t ws_size,
                              hipStream_t stream) {
    const float* node_repr = (const float*)d_in[0];
    const int*   edges     = (const int*)d_in[1];
    const float* g1 = (const float*)d_in[2];
    const float* be1 = (const float*)d_in[3];
    const float* m1 = (const float*)d_in[4];
    const float* v1 = (const float*)d_in[5];
    const float* W1 = (const float*)d_in[6];
    const float* b1 = (const float*)d_in[7];
    const float* g2 = (const float*)d_in[8];
    const float* be2 = (const float*)d_in[9];
    const float* m2 = (const float*)d_in[10];
    const float* v2 = (const float*)d_in[11];
    const float* W2 = (const float*)d_in[12];
    const float* b2 = (const float*)d_in[13];

    char* ws = (char*)d_ws;
    __bf16* W1f = (__bf16*)(ws + W1F_OFF);
    __bf16* W2f = (__bf16*)(ws + W2F_OFF);
    float* b1f = (float*)(ws + B1F_OFF);
    float* b2f = (float*)(ws + B2F_OFF);
    __bf16* T  = (__bf16*)(ws + T_OFF);
    int* offs  = (int*)(ws + OFFS_OFF);
    int* elist = (int*)(ws + ELIST_OFF);
    int* cntg  = (int*)(ws + CNTG_OFF);
    int* bofs  = (int*)(ws + BOFS_OFF);
    int* bsum  = (int*)(ws + BSUM_OFF);
    __bf16* Agg = (__bf16*)(ws + AGG_OFF);
    int* pairbuf = (int*)(ws + AGG_OFF);
    __bf16* Xb = (__bf16*)(ws + XB_OFF);
    float* out = (float*)d_out;

    hipLaunchKernelGGL(prep_kernel, dim3(256 + NBLK), dim3(256), 0, stream,
                       g1, be1, m1, v1, W1, b1, g2, be2, m2, v2, W2, b2,
                       edges, W1f, W2f, b1f, b2f, cntg);

    hipLaunchKernelGGL(sortb_kernel, dim3(NBLK), dim3(256), 0, stream, cntg, bofs, bsum);

    hipLaunchKernelGGL(sortc_kernel, dim3(NBLK), dim3(256), 0, stream,
                       edges, bsum, bofs, pairbuf);

    hipLaunchKernelGGL(p2_ffn1_kernel, dim3(NBLK + FFN1_BLKS), dim3(256), 0, stream,
                       bsum, pairbuf, elist, offs, node_repr, W1f, b1f, T, Xb);

    hipLaunchKernelGGL(agg_kernel, dim3((NN * 16 + 255) / 256), dim3(256), 0, stream,
                       T, offs, elist, Agg);

    hipLaunchKernelGGL(ffn2_kernel, dim3(FFN2_BLKS), dim3(256), 0, stream,
                       Xb, Agg, W2f, b2f, out);
}

// Round 21
// 103.377 us; speedup vs baseline: 1.1348x; 1.1348x over previous
//
#include <hip/hip_runtime.h>

#define NN 100000
#define DD 128
#define EE 640000
#define BN_EPS 1e-3f
#define NBLK 391    // ceil(NN/256); #buckets and #sort blocks
#define NTILE 6250  // NN/16 exactly
#define EPB 1637    // edges per sort block: 391*1637 >= EE
#define FFN1_BLKS 1563
#define FFN2_BLKS 768

typedef __bf16 bf16x8 __attribute__((ext_vector_type(8)));
typedef float f32x4 __attribute__((ext_vector_type(4)));

// ---- workspace byte offsets ----
#define W1F_OFF 0u
#define W2F_OFF 32768u
#define B1F_OFF 98304u
#define B2F_OFF 98816u
#define T_OFF   99328u
#define OFFS_OFF 26099328u    // NN+1 ints
#define ELIST_OFF 26899328u   // EE int; head aliases cntg+bofs (dead before p2)
#define CNTG_OFF ELIST_OFF               // 391*391 int
#define BOFS_OFF (ELIST_OFF + 611524u)   // 391*391 int
#define BSUM_OFF 29459328u
#define AGG_OFF 29464576u     // NN*128 bf16; aliases pairbuf (EE int) before agg runs
#define XB_OFF  55064576u     // NN*128 bf16

// tanh-form gelu; max |err| vs exact ~3e-4 (threshold 9.8e-2)
__device__ __forceinline__ float gelu_fast(float x) {
    float x3 = x * x * x;
    float z2 = 1.5957691216057308f * x + 0.07135481627002407f * x3;
    return x / (1.0f + __expf(-z2));
}

// prep: [0,64) fold_bias | [64,256) fold_w | [256,647) sortA per-slice bucket counts
__global__ __launch_bounds__(256) void prep_kernel(
    const float* __restrict__ g1, const float* __restrict__ be1,
    const float* __restrict__ m1, const float* __restrict__ v1,
    const float* __restrict__ W1, const float* __restrict__ b1,
    const float* __restrict__ g2, const float* __restrict__ be2,
    const float* __restrict__ m2, const float* __restrict__ v2,
    const float* __restrict__ W2, const float* __restrict__ b2,
    const int* __restrict__ edges,
    __bf16* __restrict__ W1f, __bf16* __restrict__ W2f,
    float* __restrict__ b1f, float* __restrict__ b2f,
    int* __restrict__ cntg)
{
    const int blk = blockIdx.x;
    const int t = threadIdx.x;
    if (blk < 64) {
        const int w = (blk * 256 + t) >> 6;
        const int lane = t & 63;
        if (w < 128) {
            float acc = 0.f;
            for (int k = lane; k < 128; k += 64) {
                float s = g1[k] * rsqrtf(v1[k] + BN_EPS);
                float sh = be1[k] - m1[k] * s;
                acc += sh * W1[k * 128 + w];
            }
#pragma unroll
            for (int off = 32; off > 0; off >>= 1) acc += __shfl_down(acc, off);
            if (lane == 0) b1f[w] = acc + b1[w];
        } else {
            const int n = w - 128;
            float acc = 0.f;
            for (int k = lane; k < 256; k += 64) {
                float s = g2[k] * rsqrtf(v2[k] + BN_EPS);
                float sh = be2[k] - m2[k] * s;
                acc += sh * W2[k * 128 + n];
            }
#pragma unroll
            for (int off = 32; off > 0; off >>= 1) acc += __shfl_down(acc, off);
            if (lane == 0) b2f[n] = acc + b2[n];
        }
    } else if (blk < 256) {
        int tid = (blk - 64) * 256 + t;
        if (tid < 16384) {
            int idx = tid;
            int i = idx & 7, l = (idx >> 3) & 63, nt = (idx >> 9) & 7, kt = idx >> 12;
            int k = kt * 32 + (l >> 4) * 8 + i;
            int n = nt * 16 + (l & 15);
            float s = g1[k] * rsqrtf(v1[k] + BN_EPS);
            W1f[idx] = (__bf16)(s * W1[k * 128 + n]);
        } else {
            int idx = tid - 16384;
            int i = idx & 7, l = (idx >> 3) & 63, nt = (idx >> 9) & 7, kt = idx >> 12;
            int n = nt * 16 + (l & 15);
            int row;
            if (kt < 4) {
                row = kt * 32 + (l >> 4) * 8 + i;
            } else {
                int q = (kt - 4) * 32 + (l >> 4) * 8 + i;      // physical agg col
                row = 128 + ((q & 7) * 16 + (q >> 3));
            }
            float s = g2[row] * rsqrtf(v2[row] + BN_EPS);
            W2f[idx] = (__bf16)(s * W2[row * 128 + n]);
        }
    } else {
        __shared__ int cnt[NBLK];
        const int k = blk - 256;
        for (int b = t; b < NBLK; b += 256) cnt[b] = 0;
        __syncthreads();
        const int e0 = k * EPB, e1 = min(e0 + EPB, EE);
        for (int e = e0 + t; e < e1; e += 256)
            atomicAdd(&cnt[edges[e] >> 8], 1);
        __syncthreads();
        for (int b = t; b < NBLK; b += 256) cntg[k * NBLK + b] = cnt[b];
    }
}

// sortB: bucket b; exclusive scan of cntg[k][b] over k -> bofs; total -> bsum[b]
__global__ __launch_bounds__(256) void sortb_kernel(const int* __restrict__ cntg,
                                                    int* __restrict__ bofs,
                                                    int* __restrict__ bsum)
{
    const int b = blockIdx.x, t = threadIdx.x;
    __shared__ int sp[256];
    int ia = 2 * t, ib = 2 * t + 1;
    int va = (ia < NBLK) ? cntg[ia * NBLK + b] : 0;
    int vb = (ib < NBLK) ? cntg[ib * NBLK + b] : 0;
    sp[t] = va + vb;
    __syncthreads();
    for (int off = 1; off < 256; off <<= 1) {
        int tmp = (t >= off) ? sp[t - off] : 0;
        __syncthreads();
        sp[t] += tmp;
        __syncthreads();
    }
    int pexcl = sp[t] - (va + vb);
    if (ia < NBLK) bofs[b * NBLK + ia] = pexcl;
    if (ib < NBLK) bofs[b * NBLK + ib] = pexcl + va;
    if (t == 255) bsum[b] = sp[255];
}

// sortC: inline exclusive scan of bsum seeds LDS cursors; scatter edge slice
__global__ __launch_bounds__(256) void sortc_kernel(const int* __restrict__ edges,
                                                    const int* __restrict__ bsum,
                                                    const int* __restrict__ bofs,
                                                    int* __restrict__ pairbuf)
{
    __shared__ int sp[256];
    __shared__ int cur[NBLK];
    const int k = blockIdx.x, t = threadIdx.x;
    int ia = 2 * t, ib = 2 * t + 1;
    int va = (ia < NBLK) ? bsum[ia] : 0;
    int vb = (ib < NBLK) ? bsum[ib] : 0;
    sp[t] = va + vb;
    __syncthreads();
    for (int off = 1; off < 256; off <<= 1) {
        int tmp = (t >= off) ? sp[t - off] : 0;
        __syncthreads();
        sp[t] += tmp;
        __syncthreads();
    }
    int pexcl = sp[t] - (va + vb);
    if (ia < NBLK) cur[ia] = pexcl + bofs[ia * NBLK + k];
    if (ib < NBLK) cur[ib] = pexcl + va + bofs[ib * NBLK + k];
    __syncthreads();
    const int e0 = k * EPB, e1 = min(e0 + EPB, EE);
    for (int e = e0 + t; e < e1; e += 256) {
        int dst = edges[e];
        int src = edges[EE + e];
        int pos = atomicAdd(&cur[dst >> 8], 1);
        pairbuf[pos] = (src << 8) | (dst & 255);
    }
}

// fused: [0,NBLK) p2 (bucket-local CSR finalize; 2KB LDS) |
// [NBLK,+1563) ffn1: 1 tile/wave, ALL 32 B-frags + 8 X-loads issued up front
// (one wait, then 16 straight MFMAs) — removes the serial B-group waits.
// T layout (permuted cols) and 16B stores identical to R18.
__global__ __launch_bounds__(256) void p2_ffn1_kernel(
    const int* __restrict__ bsum, const int* __restrict__ pairbuf,
    int* __restrict__ elist, int* __restrict__ offs,
    const float* __restrict__ X, const __bf16* __restrict__ W1f,
    const float* __restrict__ b1f, __bf16* __restrict__ T,
    __bf16* __restrict__ Xb)
{
    __shared__ int sArr[256];
    __shared__ int cur[256];
    __shared__ int red[4];
    const int t = threadIdx.x;
    if (blockIdx.x < NBLK) {
        const int b = blockIdx.x;
        int part = 0;
        for (int i = t; i < b; i += 256) part += bsum[i];
#pragma unroll
        for (int off = 32; off > 0; off >>= 1) part += __shfl_down(part, off);
        if ((t & 63) == 0) red[t >> 6] = part;
        cur[t] = 0;
        __syncthreads();
        const int start = red[0] + red[1] + red[2] + red[3];
        const int end = start + bsum[b];
        for (int e = start + t; e < end; e += 256)
            atomicAdd(&cur[pairbuf[e] & 255], 1);
        __syncthreads();
        int v = cur[t];
        sArr[t] = v;
        __syncthreads();
        for (int off = 1; off < 256; off <<= 1) {
            int tmp = (t >= off) ? sArr[t - off] : 0;
            __syncthreads();
            sArr[t] += tmp;
            __syncthreads();
        }
        int ex = sArr[t] - v + start;
        const int node = b * 256 + t;
        if (node <= NN) offs[node] = ex;   // node==NN -> sentinel EE
        __syncthreads();
        cur[t] = ex;
        __syncthreads();
        for (int e = start + t; e < end; e += 256) {
            int item = pairbuf[e];
            int pos = atomicAdd(&cur[item & 255], 1);
            elist[pos] = item >> 8;
        }
        return;
    }

    const int wave = t >> 6;
    const int lane = t & 63;
    const int tile = (blockIdx.x - NBLK) * 4 + wave;
    if (tile >= NTILE) return;
    const int c = lane & 15, kh = lane >> 4;

    const size_t rowb = (size_t)(tile * 16 + c) * DD;
    const float* xr = X + rowb + kh * 8;

    // issue ALL loads: 8 X + 32 B fragments (one vmcnt wait covers everything)
    f32x4 r0[4], r1[4];
#pragma unroll
    for (int q = 0; q < 4; ++q) {
        r0[q] = *(const f32x4*)(xr + q * 32);
        r1[q] = *(const f32x4*)(xr + q * 32 + 4);
    }
    bf16x8 B[4][8];
#pragma unroll
    for (int kt = 0; kt < 4; ++kt)
#pragma unroll
        for (int nt = 0; nt < 8; ++nt)
            B[kt][nt] = *(const bf16x8*)(W1f + ((size_t)((kt * 8 + nt) * 64 + lane)) * 8);

    bf16x8 af[4];
#pragma unroll
    for (int kt = 0; kt < 4; ++kt) {
        bf16x8 fa;
#pragma unroll
        for (int i = 0; i < 4; ++i) { fa[i] = (__bf16)r0[kt][i]; fa[4 + i] = (__bf16)r1[kt][i]; }
        af[kt] = fa;
        *(bf16x8*)(Xb + rowb + kt * 32 + kh * 8) = fa;
    }

    f32x4 acc[8] = {};
#pragma unroll
    for (int kt = 0; kt < 4; ++kt)
#pragma unroll
        for (int nt = 0; nt < 8; ++nt)
            acc[nt] = __builtin_amdgcn_mfma_f32_16x16x32_bf16(af[kt], B[kt][nt], acc[nt], 0, 0, 0);

    float bias[8];
#pragma unroll
    for (int nt = 0; nt < 8; ++nt) bias[nt] = b1f[nt * 16 + c];

#pragma unroll
    for (int r = 0; r < 4; ++r) {
        int row = tile * 16 + kh * 4 + r;
        bf16x8 o;
#pragma unroll
        for (int nt = 0; nt < 8; ++nt)
            o[nt] = (__bf16)gelu_fast(acc[nt][r] + bias[nt]);
        *(bf16x8*)(T + (size_t)row * DD + c * 8) = o;
    }
}

// gather-mean: 16 threads/node; coalesced elist load + __shfl broadcast
__global__ __launch_bounds__(256) void agg_kernel(
    const __bf16* __restrict__ T, const int* __restrict__ offs,
    const int* __restrict__ elist, __bf16* __restrict__ Agg)
{
    int t = blockIdx.x * 256 + threadIdx.x;
    int node = t >> 4, j = t & 15;
    if (node >= NN) return;
    const int lane = threadIdx.x & 63;
    const int gbase = lane & 48;
    const int beg = offs[node];
    const int end = offs[node + 1];
    const int d = end - beg;
    float acc[8] = {};
    for (int eb = beg; eb < end; eb += 16) {
        int me = eb + (lane & 15);
        int sv = (me < end) ? elist[me] : 0;
        int cnt = min(end - eb, 16);
        int i = 0;
        for (; i + 3 < cnt; i += 4) {
            int s0 = __shfl(sv, gbase + i);
            int s1 = __shfl(sv, gbase + i + 1);
            int s2 = __shfl(sv, gbase + i + 2);
            int s3 = __shfl(sv, gbase + i + 3);
            bf16x8 v0 = *(const bf16x8*)(T + (size_t)s0 * DD + j * 8);
            bf16x8 v1 = *(const bf16x8*)(T + (size_t)s1 * DD + j * 8);
            bf16x8 v2 = *(const bf16x8*)(T + (size_t)s2 * DD + j * 8);
            bf16x8 v3 = *(const bf16x8*)(T + (size_t)s3 * DD + j * 8);
#pragma unroll
            for (int q = 0; q < 8; ++q)
                acc[q] += ((float)v0[q] + (float)v1[q]) + ((float)v2[q] + (float)v3[q]);
        }
        for (; i < cnt; ++i) {
            int s0 = __shfl(sv, gbase + i);
            bf16x8 v0 = *(const bf16x8*)(T + (size_t)s0 * DD + j * 8);
#pragma unroll
            for (int q = 0; q < 8; ++q) acc[q] += (float)v0[q];
        }
    }
    const float inv = 1.0f / fmaxf((float)d, 1.0f);
    bf16x8 o;
#pragma unroll
    for (int q = 0; q < 8; ++q) o[q] = (__bf16)(acc[q] * inv);
    *(bf16x8*)(Agg + (size_t)node * DD + j * 8) = o;
}

// out = gelu([Xb, Agg] @ W2f + b2f); persistent-B quarters, grid-stride tiles,
// next-tile A prefetch (named buffers).
#define FFN2_LOAD(TT, XA, GA)                                              \
    {                                                                      \
        const size_t rb = (size_t)((TT) * 16 + c) * DD + kh * 8;           \
        _Pragma("unroll")                                                  \
        for (int q = 0; q < 4; ++q) {                                      \
            XA[q] = *(const bf16x8*)(Xb + rb + q * 32);                    \
            GA[q] = *(const bf16x8*)(Agg + rb + q * 32);                   \
        }                                                                  \
    }

#define FFN2_COMP(TT, XA, GA)                                              \
    {                                                                      \
        f32x4 acc0 = {}, acc1 = {};                                        \
        _Pragma("unroll")                                                  \
        for (int kt = 0; kt < 4; ++kt) {                                   \
            acc0 = __builtin_amdgcn_mfma_f32_16x16x32_bf16(XA[kt], Bf[kt][0], acc0, 0, 0, 0); \
            acc1 = __builtin_amdgcn_mfma_f32_16x16x32_bf16(XA[kt], Bf[kt][1], acc1, 0, 0, 0); \
        }                                                                  \
        _Pragma("unroll")                                                  \
        for (int kt = 0; kt < 4; ++kt) {                                   \
            acc0 = __builtin_amdgcn_mfma_f32_16x16x32_bf16(GA[kt], Bf[4 + kt][0], acc0, 0, 0, 0); \
            acc1 = __builtin_amdgcn_mfma_f32_16x16x32_bf16(GA[kt], Bf[4 + kt][1], acc1, 0, 0, 0); \
        }                                                                  \
        _Pragma("unroll")                                                  \
        for (int r = 0; r < 4; ++r) {                                      \
            int row = (TT) * 16 + kh * 4 + r;                              \
            out[(size_t)row * DD + (w * 2) * 16 + c] = gelu_fast(acc0[r] + bias0); \
            out[(size_t)row * DD + (w * 2 + 1) * 16 + c] = gelu_fast(acc1[r] + bias1); \
        }                                                                  \
    }

__global__ __launch_bounds__(256) void ffn2_kernel(
    const __bf16* __restrict__ Xb, const __bf16* __restrict__ Agg,
    const __bf16* __restrict__ W2f, const float* __restrict__ b2f,
    float* __restrict__ out)
{
    const int w = threadIdx.x >> 6;        // wave = quarter (nt 2w, 2w+1)
    const int lane = threadIdx.x & 63;
    const int c = lane & 15, kh = lane >> 4;
    const int G = gridDim.x;

    bf16x8 Bf[8][2];
#pragma unroll
    for (int kt = 0; kt < 8; ++kt) {
        Bf[kt][0] = *(const bf16x8*)(W2f + ((size_t)((kt * 8 + w * 2) * 64 + lane)) * 8);
        Bf[kt][1] = *(const bf16x8*)(W2f + ((size_t)((kt * 8 + w * 2 + 1) * 64 + lane)) * 8);
    }
    const float bias0 = b2f[(w * 2) * 16 + c];
    const float bias1 = b2f[(w * 2 + 1) * 16 + c];

    int tile = blockIdx.x;
    if (tile >= NTILE) return;
    bf16x8 xa[4], ga[4], xb2[4], gb[4];
    FFN2_LOAD(tile, xa, ga);
    while (true) {
        int t2 = tile + G;
        if (t2 < NTILE) FFN2_LOAD(t2, xb2, gb);
        FFN2_COMP(tile, xa, ga);
        if (t2 >= NTILE) break;
        int t3 = t2 + G;
        if (t3 < NTILE) FFN2_LOAD(t3, xa, ga);
        FFN2_COMP(t2, xb2, gb);
        if (t3 >= NTILE) break;
        tile = t3;
    }
}

extern "C" void kernel_launch(void* const* d_in, const int* in_sizes, int n_in,
                              void* d_out, int out_size, void* d_ws, size_t ws_size,
                              hipStream_t stream) {
    const float* node_repr = (const float*)d_in[0];
    const int*   edges     = (const int*)d_in[1];
    const float* g1 = (const float*)d_in[2];
    const float* be1 = (const float*)d_in[3];
    const float* m1 = (const float*)d_in[4];
    const float* v1 = (const float*)d_in[5];
    const float* W1 = (const float*)d_in[6];
    const float* b1 = (const float*)d_in[7];
    const float* g2 = (const float*)d_in[8];
    const float* be2 = (const float*)d_in[9];
    const float* m2 = (const float*)d_in[10];
    const float* v2 = (const float*)d_in[11];
    const float* W2 = (const float*)d_in[12];
    const float* b2 = (const float*)d_in[13];

    char* ws = (char*)d_ws;
    __bf16* W1f = (__bf16*)(ws + W1F_OFF);
    __bf16* W2f = (__bf16*)(ws + W2F_OFF);
    float* b1f = (float*)(ws + B1F_OFF);
    float* b2f = (float*)(ws + B2F_OFF);
    __bf16* T  = (__bf16*)(ws + T_OFF);
    int* offs  = (int*)(ws + OFFS_OFF);
    int* elist = (int*)(ws + ELIST_OFF);
    int* cntg  = (int*)(ws + CNTG_OFF);
    int* bofs  = (int*)(ws + BOFS_OFF);
    int* bsum  = (int*)(ws + BSUM_OFF);
    __bf16* Agg = (__bf16*)(ws + AGG_OFF);
    int* pairbuf = (int*)(ws + AGG_OFF);
    __bf16* Xb = (__bf16*)(ws + XB_OFF);
    float* out = (float*)d_out;

    hipLaunchKernelGGL(prep_kernel, dim3(256 + NBLK), dim3(256), 0, stream,
                       g1, be1, m1, v1, W1, b1, g2, be2, m2, v2, W2, b2,
                       edges, W1f, W2f, b1f, b2f, cntg);

    hipLaunchKernelGGL(sortb_kernel, dim3(NBLK), dim3(256), 0, stream, cntg, bofs, bsum);

    hipLaunchKernelGGL(sortc_kernel, dim3(NBLK), dim3(256), 0, stream,
                       edges, bsum, bofs, pairbuf);

    hipLaunchKernelGGL(p2_ffn1_kernel, dim3(NBLK + FFN1_BLKS), dim3(256), 0, stream,
                       bsum, pairbuf, elist, offs, node_repr, W1f, b1f, T, Xb);

    hipLaunchKernelGGL(agg_kernel, dim3((NN * 16 + 255) / 256), dim3(256), 0, stream,
                       T, offs, elist, Agg);

    hipLaunchKernelGGL(ffn2_kernel, dim3(FFN2_BLKS), dim3(256), 0, stream,
                       Xb, Agg, W2f, b2f, out);
}

// Round 22
// 99.490 us; speedup vs baseline: 1.1791x; 1.0391x over previous
//
#include <hip/hip_runtime.h>

#define NN 100000
#define DD 128
#define EE 640000
#define BN_EPS 1e-3f
#define NBLK 391    // ceil(NN/256); #buckets and #sort blocks
#define NTILE 6250  // NN/16 exactly
#define EPB 1637    // edges per sort block: 391*1637 >= EE
#define FFN1_BLKS 1563
#define FFN2_BLKS 768
#define LEMAX 4096  // LDS elist capacity per bucket (mean 1638, sd ~40)

typedef __bf16 bf16x8 __attribute__((ext_vector_type(8)));
typedef float f32x4 __attribute__((ext_vector_type(4)));

// ---- workspace byte offsets ----
#define W1F_OFF 0u
#define W2F_OFF 32768u
#define B1F_OFF 98304u
#define B2F_OFF 98816u
#define T_OFF   99328u        // NN*128 bf16 = 25,600,000
#define CNTG_OFF 25699328u               // 391*391 int
#define BOFS_OFF (25699328u + 611524u)   // 391*391 int
#define BSUM_OFF 26922376u               // 391 int
#define AGG_OFF  26926476u   // align up -> use 26926592
#define AGG_OFF2 26926592u   // NN*128 bf16 = 25,600,000
#define XB_OFF   52526592u   // NN*128 bf16 = 25,600,000
#define PAIR_OFF 78126592u   // EE int = 2,560,000  (end ~80.7 MB < ws)

// tanh-form gelu; max |err| vs exact ~3e-4 (threshold 9.8e-2)
__device__ __forceinline__ float gelu_fast(float x) {
    float x3 = x * x * x;
    float z2 = 1.5957691216057308f * x + 0.07135481627002407f * x3;
    return x / (1.0f + __expf(-z2));
}

// prep: [0,64) fold_bias | [64,256) fold_w | [256,647) sortA per-slice bucket counts
__global__ __launch_bounds__(256) void prep_kernel(
    const float* __restrict__ g1, const float* __restrict__ be1,
    const float* __restrict__ m1, const float* __restrict__ v1,
    const float* __restrict__ W1, const float* __restrict__ b1,
    const float* __restrict__ g2, const float* __restrict__ be2,
    const float* __restrict__ m2, const float* __restrict__ v2,
    const float* __restrict__ W2, const float* __restrict__ b2,
    const int* __restrict__ edges,
    __bf16* __restrict__ W1f, __bf16* __restrict__ W2f,
    float* __restrict__ b1f, float* __restrict__ b2f,
    int* __restrict__ cntg)
{
    const int blk = blockIdx.x;
    const int t = threadIdx.x;
    if (blk < 64) {
        const int w = (blk * 256 + t) >> 6;
        const int lane = t & 63;
        if (w < 128) {
            float acc = 0.f;
            for (int k = lane; k < 128; k += 64) {
                float s = g1[k] * rsqrtf(v1[k] + BN_EPS);
                float sh = be1[k] - m1[k] * s;
                acc += sh * W1[k * 128 + w];
            }
#pragma unroll
            for (int off = 32; off > 0; off >>= 1) acc += __shfl_down(acc, off);
            if (lane == 0) b1f[w] = acc + b1[w];
        } else {
            const int n = w - 128;
            float acc = 0.f;
            for (int k = lane; k < 256; k += 64) {
                float s = g2[k] * rsqrtf(v2[k] + BN_EPS);
                float sh = be2[k] - m2[k] * s;
                acc += sh * W2[k * 128 + n];
            }
#pragma unroll
            for (int off = 32; off > 0; off >>= 1) acc += __shfl_down(acc, off);
            if (lane == 0) b2f[n] = acc + b2[n];
        }
    } else if (blk < 256) {
        int tid = (blk - 64) * 256 + t;
        if (tid < 16384) {
            int idx = tid;
            int i = idx & 7, l = (idx >> 3) & 63, nt = (idx >> 9) & 7, kt = idx >> 12;
            int k = kt * 32 + (l >> 4) * 8 + i;
            int n = nt * 16 + (l & 15);
            float s = g1[k] * rsqrtf(v1[k] + BN_EPS);
            W1f[idx] = (__bf16)(s * W1[k * 128 + n]);
        } else {
            int idx = tid - 16384;
            int i = idx & 7, l = (idx >> 3) & 63, nt = (idx >> 9) & 7, kt = idx >> 12;
            int n = nt * 16 + (l & 15);
            int row;
            if (kt < 4) {
                row = kt * 32 + (l >> 4) * 8 + i;
            } else {
                int q = (kt - 4) * 32 + (l >> 4) * 8 + i;      // physical agg col
                row = 128 + ((q & 7) * 16 + (q >> 3));
            }
            float s = g2[row] * rsqrtf(v2[row] + BN_EPS);
            W2f[idx] = (__bf16)(s * W2[row * 128 + n]);
        }
    } else {
        __shared__ int cnt[NBLK];
        const int k = blk - 256;
        for (int b = t; b < NBLK; b += 256) cnt[b] = 0;
        __syncthreads();
        const int e0 = k * EPB, e1 = min(e0 + EPB, EE);
        for (int e = e0 + t; e < e1; e += 256)
            atomicAdd(&cnt[edges[e] >> 8], 1);
        __syncthreads();
        for (int b = t; b < NBLK; b += 256) cntg[k * NBLK + b] = cnt[b];
    }
}

// sortB: bucket b; exclusive scan of cntg[k][b] over k -> bofs; total -> bsum[b]
__global__ __launch_bounds__(256) void sortb_kernel(const int* __restrict__ cntg,
                                                    int* __restrict__ bofs,
                                                    int* __restrict__ bsum)
{
    const int b = blockIdx.x, t = threadIdx.x;
    __shared__ int sp[256];
    int ia = 2 * t, ib = 2 * t + 1;
    int va = (ia < NBLK) ? cntg[ia * NBLK + b] : 0;
    int vb = (ib < NBLK) ? cntg[ib * NBLK + b] : 0;
    sp[t] = va + vb;
    __syncthreads();
    for (int off = 1; off < 256; off <<= 1) {
        int tmp = (t >= off) ? sp[t - off] : 0;
        __syncthreads();
        sp[t] += tmp;
        __syncthreads();
    }
    int pexcl = sp[t] - (va + vb);
    if (ia < NBLK) bofs[b * NBLK + ia] = pexcl;
    if (ib < NBLK) bofs[b * NBLK + ib] = pexcl + va;
    if (t == 255) bsum[b] = sp[255];
}

// fused: [0,NBLK) sortC | [NBLK,+1563) ffn1 (all loads up front, emits T + Xb)
__global__ __launch_bounds__(256) void sortc_ffn1_kernel(
    const int* __restrict__ edges, const int* __restrict__ bsum,
    const int* __restrict__ bofs, int* __restrict__ pairbuf,
    const float* __restrict__ X, const __bf16* __restrict__ W1f,
    const float* __restrict__ b1f, __bf16* __restrict__ T,
    __bf16* __restrict__ Xb)
{
    __shared__ int sp[256];
    __shared__ int cur[NBLK];
    const int t = threadIdx.x;
    if (blockIdx.x < NBLK) {
        const int k = blockIdx.x;
        int ia = 2 * t, ib = 2 * t + 1;
        int va = (ia < NBLK) ? bsum[ia] : 0;
        int vb = (ib < NBLK) ? bsum[ib] : 0;
        sp[t] = va + vb;
        __syncthreads();
        for (int off = 1; off < 256; off <<= 1) {
            int tmp = (t >= off) ? sp[t - off] : 0;
            __syncthreads();
            sp[t] += tmp;
            __syncthreads();
        }
        int pexcl = sp[t] - (va + vb);
        if (ia < NBLK) cur[ia] = pexcl + bofs[ia * NBLK + k];
        if (ib < NBLK) cur[ib] = pexcl + va + bofs[ib * NBLK + k];
        __syncthreads();
        const int e0 = k * EPB, e1 = min(e0 + EPB, EE);
        for (int e = e0 + t; e < e1; e += 256) {
            int dst = edges[e];
            int src = edges[EE + e];
            int pos = atomicAdd(&cur[dst >> 8], 1);
            pairbuf[pos] = (src << 8) | (dst & 255);
        }
        return;
    }

    const int wave = t >> 6;
    const int lane = t & 63;
    const int tile = (blockIdx.x - NBLK) * 4 + wave;
    if (tile >= NTILE) return;
    const int c = lane & 15, kh = lane >> 4;

    const size_t rowb = (size_t)(tile * 16 + c) * DD;
    const float* xr = X + rowb + kh * 8;

    f32x4 r0[4], r1[4];
#pragma unroll
    for (int q = 0; q < 4; ++q) {
        r0[q] = *(const f32x4*)(xr + q * 32);
        r1[q] = *(const f32x4*)(xr + q * 32 + 4);
    }
    bf16x8 B[4][8];
#pragma unroll
    for (int kt = 0; kt < 4; ++kt)
#pragma unroll
        for (int nt = 0; nt < 8; ++nt)
            B[kt][nt] = *(const bf16x8*)(W1f + ((size_t)((kt * 8 + nt) * 64 + lane)) * 8);

    bf16x8 af[4];
#pragma unroll
    for (int kt = 0; kt < 4; ++kt) {
        bf16x8 fa;
#pragma unroll
        for (int i = 0; i < 4; ++i) { fa[i] = (__bf16)r0[kt][i]; fa[4 + i] = (__bf16)r1[kt][i]; }
        af[kt] = fa;
        *(bf16x8*)(Xb + rowb + kt * 32 + kh * 8) = fa;
    }

    f32x4 acc[8] = {};
#pragma unroll
    for (int kt = 0; kt < 4; ++kt)
#pragma unroll
        for (int nt = 0; nt < 8; ++nt)
            acc[nt] = __builtin_amdgcn_mfma_f32_16x16x32_bf16(af[kt], B[kt][nt], acc[nt], 0, 0, 0);

    float bias[8];
#pragma unroll
    for (int nt = 0; nt < 8; ++nt) bias[nt] = b1f[nt * 16 + c];

#pragma unroll
    for (int r = 0; r < 4; ++r) {
        int row = tile * 16 + kh * 4 + r;
        bf16x8 o;
#pragma unroll
        for (int nt = 0; nt < 8; ++nt)
            o[nt] = (__bf16)gelu_fast(acc[nt][r] + bias[nt]);
        *(bf16x8*)(T + (size_t)row * DD + c * 8) = o;
    }
}

// p2agg: one 1024-thread block per bucket. CSR finalize entirely in LDS
// (hist -> scan -> scatter src ids), then barrier-free gather-mean of T rows
// (16 threads/node, 4-edge unroll) -> Agg. elist/offs never touch global.
__global__ __launch_bounds__(1024) void p2agg_kernel(
    const int* __restrict__ bsum, const int* __restrict__ pairbuf,
    const __bf16* __restrict__ T, __bf16* __restrict__ Agg)
{
    __shared__ int cnt[256];
    __shared__ int sArr[256];
    __shared__ int loff[257];
    __shared__ int red[16];
    __shared__ int lelist[LEMAX];
    const int b = blockIdx.x, t = threadIdx.x;
    const int lane = t & 63;

    int part = 0;
    for (int i = t; i < b; i += 1024) part += bsum[i];
#pragma unroll
    for (int off = 32; off > 0; off >>= 1) part += __shfl_down(part, off);
    if (lane == 0) red[t >> 6] = part;
    if (t < 256) cnt[t] = 0;
    __syncthreads();
    int start = 0;
#pragma unroll
    for (int i = 0; i < 16; ++i) start += red[i];
    const int tot = bsum[b];
    const int end = start + tot;

    for (int e = start + t; e < end; e += 1024)
        atomicAdd(&cnt[pairbuf[e] & 255], 1);
    __syncthreads();

    if (t < 256) sArr[t] = cnt[t];
    __syncthreads();
    for (int off = 1; off < 256; off <<= 1) {
        int tmp = (t < 256 && t >= off) ? sArr[t - off] : 0;
        __syncthreads();
        if (t < 256) sArr[t] += tmp;
        __syncthreads();
    }
    if (t < 256) {
        int ex = sArr[t] - cnt[t];
        loff[t] = ex;
        cnt[t] = ex;
    }
    if (t == 255) loff[256] = sArr[255];
    __syncthreads();

    for (int e = start + t; e < end; e += 1024) {
        int item = pairbuf[e];
        int pos = atomicAdd(&cnt[item & 255], 1);
        if (pos < LEMAX) lelist[pos] = item >> 8;
    }
    __syncthreads();

    const int j = t & 15;
    const int nl = t >> 4;
#pragma unroll
    for (int round = 0; round < 4; ++round) {
        const int nodeL = round * 64 + nl;
        const int node = b * 256 + nodeL;
        if (node >= NN) continue;
        const int lb = loff[nodeL], le = loff[nodeL + 1];
        float acc[8] = {};
        int e = lb;
        for (; e + 3 < le; e += 4) {
            int s0 = lelist[e], s1 = lelist[e + 1], s2 = lelist[e + 2], s3 = lelist[e + 3];
            bf16x8 v0 = *(const bf16x8*)(T + (size_t)s0 * DD + j * 8);
            bf16x8 v1 = *(const bf16x8*)(T + (size_t)s1 * DD + j * 8);
            bf16x8 v2 = *(const bf16x8*)(T + (size_t)s2 * DD + j * 8);
            bf16x8 v3 = *(const bf16x8*)(T + (size_t)s3 * DD + j * 8);
#pragma unroll
            for (int q = 0; q < 8; ++q)
                acc[q] += ((float)v0[q] + (float)v1[q]) + ((float)v2[q] + (float)v3[q]);
        }
        for (; e < le; ++e) {
            int s0 = lelist[e];
            bf16x8 v0 = *(const bf16x8*)(T + (size_t)s0 * DD + j * 8);
#pragma unroll
            for (int q = 0; q < 8; ++q) acc[q] += (float)v0[q];
        }
        const float inv = 1.0f / fmaxf((float)(le - lb), 1.0f);
        bf16x8 o;
#pragma unroll
        for (int q = 0; q < 8; ++q) o[q] = (__bf16)(acc[q] * inv);
        *(bf16x8*)(Agg + (size_t)node * DD + j * 8) = o;
    }
}

// out = gelu([Xb, Agg] @ W2f + b2f); persistent-B quarters, grid-stride tiles,
// next-tile A prefetch (named buffers).
#define FFN2_LOAD(TT, XA, GA)                                              \
    {                                                                      \
        const size_t rb = (size_t)((TT) * 16 + c) * DD + kh * 8;           \
        _Pragma("unroll")                                                  \
        for (int q = 0; q < 4; ++q) {                                      \
            XA[q] = *(const bf16x8*)(Xb + rb + q * 32);                    \
            GA[q] = *(const bf16x8*)(Agg + rb + q * 32);                   \
        }                                                                  \
    }

#define FFN2_COMP(TT, XA, GA)                                              \
    {                                                                      \
        f32x4 acc0 = {}, acc1 = {};                                        \
        _Pragma("unroll")                                                  \
        for (int kt = 0; kt < 4; ++kt) {                                   \
            acc0 = __builtin_amdgcn_mfma_f32_16x16x32_bf16(XA[kt], Bf[kt][0], acc0, 0, 0, 0); \
            acc1 = __builtin_amdgcn_mfma_f32_16x16x32_bf16(XA[kt], Bf[kt][1], acc1, 0, 0, 0); \
        }                                                                  \
        _Pragma("unroll")                                                  \
        for (int kt = 0; kt < 4; ++kt) {                                   \
            acc0 = __builtin_amdgcn_mfma_f32_16x16x32_bf16(GA[kt], Bf[4 + kt][0], acc0, 0, 0, 0); \
            acc1 = __builtin_amdgcn_mfma_f32_16x16x32_bf16(GA[kt], Bf[4 + kt][1], acc1, 0, 0, 0); \
        }                                                                  \
        _Pragma("unroll")                                                  \
        for (int r = 0; r < 4; ++r) {                                      \
            int row = (TT) * 16 + kh * 4 + r;                              \
            out[(size_t)row * DD + (w * 2) * 16 + c] = gelu_fast(acc0[r] + bias0); \
            out[(size_t)row * DD + (w * 2 + 1) * 16 + c] = gelu_fast(acc1[r] + bias1); \
        }                                                                  \
    }

__global__ __launch_bounds__(256) void ffn2_kernel(
    const __bf16* __restrict__ Xb, const __bf16* __restrict__ Agg,
    const __bf16* __restrict__ W2f, const float* __restrict__ b2f,
    float* __restrict__ out)
{
    const int w = threadIdx.x >> 6;
    const int lane = threadIdx.x & 63;
    const int c = lane & 15, kh = lane >> 4;
    const int G = gridDim.x;

    bf16x8 Bf[8][2];
#pragma unroll
    for (int kt = 0; kt < 8; ++kt) {
        Bf[kt][0] = *(const bf16x8*)(W2f + ((size_t)((kt * 8 + w * 2) * 64 + lane)) * 8);
        Bf[kt][1] = *(const bf16x8*)(W2f + ((size_t)((kt * 8 + w * 2 + 1) * 64 + lane)) * 8);
    }
    const float bias0 = b2f[(w * 2) * 16 + c];
    const float bias1 = b2f[(w * 2 + 1) * 16 + c];

    int tile = blockIdx.x;
    if (tile >= NTILE) return;
    bf16x8 xa[4], ga[4], xb2[4], gb[4];
    FFN2_LOAD(tile, xa, ga);
    while (true) {
        int t2 = tile + G;
        if (t2 < NTILE) FFN2_LOAD(t2, xb2, gb);
        FFN2_COMP(tile, xa, ga);
        if (t2 >= NTILE) break;
        int t3 = t2 + G;
        if (t3 < NTILE) FFN2_LOAD(t3, xa, ga);
        FFN2_COMP(t2, xb2, gb);
        if (t3 >= NTILE) break;
        tile = t3;
    }
}

extern "C" void kernel_launch(void* const* d_in, const int* in_sizes, int n_in,
                              void* d_out, int out_size, void* d_ws, size_t ws_size,
                              hipStream_t stream) {
    const float* node_repr = (const float*)d_in[0];
    const int*   edges     = (const int*)d_in[1];
    const float* g1 = (const float*)d_in[2];
    const float* be1 = (const float*)d_in[3];
    const float* m1 = (const float*)d_in[4];
    const float* v1 = (const float*)d_in[5];
    const float* W1 = (const float*)d_in[6];
    const float* b1 = (const float*)d_in[7];
    const float* g2 = (const float*)d_in[8];
    const float* be2 = (const float*)d_in[9];
    const float* m2 = (const float*)d_in[10];
    const float* v2 = (const float*)d_in[11];
    const float* W2 = (const float*)d_in[12];
    const float* b2 = (const float*)d_in[13];

    char* ws = (char*)d_ws;
    __bf16* W1f = (__bf16*)(ws + W1F_OFF);
    __bf16* W2f = (__bf16*)(ws + W2F_OFF);
    float* b1f = (float*)(ws + B1F_OFF);
    float* b2f = (float*)(ws + B2F_OFF);
    __bf16* T  = (__bf16*)(ws + T_OFF);
    int* cntg  = (int*)(ws + CNTG_OFF);
    int* bofs  = (int*)(ws + BOFS_OFF);
    int* bsum  = (int*)(ws + BSUM_OFF);
    __bf16* Agg = (__bf16*)(ws + AGG_OFF2);
    __bf16* Xb  = (__bf16*)(ws + XB_OFF);
    int* pairbuf = (int*)(ws + PAIR_OFF);   // dedicated region (Agg no longer aliasable)
    float* out = (float*)d_out;

    hipLaunchKernelGGL(prep_kernel, dim3(256 + NBLK), dim3(256), 0, stream,
                       g1, be1, m1, v1, W1, b1, g2, be2, m2, v2, W2, b2,
                       edges, W1f, W2f, b1f, b2f, cntg);

    hipLaunchKernelGGL(sortb_kernel, dim3(NBLK), dim3(256), 0, stream, cntg, bofs, bsum);

    hipLaunchKernelGGL(sortc_ffn1_kernel, dim3(NBLK + FFN1_BLKS), dim3(256), 0, stream,
                       edges, bsum, bofs, pairbuf, node_repr, W1f, b1f, T, Xb);

    hipLaunchKernelGGL(p2agg_kernel, dim3(NBLK), dim3(1024), 0, stream,
                       bsum, pairbuf, T, Agg);

    hipLaunchKernelGGL(ffn2_kernel, dim3(FFN2_BLKS), dim3(256), 0, stream,
                       Xb, Agg, W2f, b2f, out);
}